// Round 9
// baseline (1293.248 us; speedup 1.0000x reference)
//
#include <hip/hip_runtime.h>
#include <math.h>

#define CCH 64
#define HH 480
#define WW 360
#define KK 32
#define HR 64
#define WR 2048
#define NPIX (HH*WW)            // 172800
#define RFNPIX (HR*WR)          // 131072
#define ZOFF 16777216u          // byte offset of zero line in rfT16
#define NEGOFF 16777344u        // byte offset of -3.4e38 sentinel line
#define GRID_S 900              // persistent sampler grid (<=4 blocks/CU co-resident)
#define PPW 24                  // pairs per wave: 900*4*24 = 86400 exactly

typedef __attribute__((ext_vector_type(8))) short short8;
typedef __attribute__((ext_vector_type(4))) float f32x4;
typedef __attribute__((ext_vector_type(4))) int  int4_;

__device__ __forceinline__ ushort f2bf(float f) {        // RTN f32->bf16
    uint u = __float_as_uint(f);
    return (ushort)((u + 0x7fffu + ((u >> 16) & 1u)) >> 16);
}

// ---------------------------------------------------------------------------
// Weight prep: pack conv weights into MFMA A-fragment order, bf16.
// ---------------------------------------------------------------------------
__global__ __launch_bounds__(256) void k_wprep(const float* __restrict__ fw,
                                               const float* __restrict__ aw,
                                               ushort* __restrict__ wA1,
                                               ushort* __restrict__ wA2) {
    int t = blockIdx.x * 256 + threadIdx.x;
    if (t < 73728) {                                   // conv1: 4 chunks (128 ci)
        int j = t & 7, ln = (t >> 3) & 63, Mf = (t >> 9) & 3, rem = t >> 11;
        int tap = rem % 9, c = rem / 9;
        int o = Mf * 16 + (ln & 15);
        int ci = c * 32 + ((ln >> 4) & 3) * 8 + j;
        wA1[t] = f2bf(fw[(o * 128 + ci) * 9 + tap]);
    } else if (t < 73728 + 36864) {                    // conv2: 2 chunks (64 ci)
        int i = t - 73728;
        int j = i & 7, ln = (i >> 3) & 63, Mf = (i >> 9) & 3, rem = i >> 11;
        int tap = rem % 9, c = rem / 9;
        int o = Mf * 16 + (ln & 15);
        int ci = c * 32 + ((ln >> 4) & 3) * 8 + j;
        wA2[i] = f2bf(aw[(o * 64 + ci) * 9 + tap]);
    }
}

// ---------------------------------------------------------------------------
// Transpose f32 [64][npix] -> bf16 channel-last [npix][rowShorts] (cols 0..63)
// ---------------------------------------------------------------------------
__global__ __launch_bounds__(256) void k_tr(const float* __restrict__ src,
                                            ushort* __restrict__ dst,
                                            int npix, int rowShorts) {
    __shared__ float lds[64][65];
    int t = threadIdx.x;
    int pix0 = blockIdx.x * 64;
    int lx = t & 63, ty = t >> 6;
    #pragma unroll
    for (int cc = 0; cc < 64; cc += 4) {
        int c = cc + ty;
        lds[c][lx] = src[(size_t)c * npix + pix0 + lx];
    }
    __syncthreads();
    int cp = t & 31, po = t >> 5;        // cp = channel pair, po = pixel offset
    #pragma unroll
    for (int pl = po; pl < 64; pl += 8) {
        uint u = (uint)f2bf(lds[2 * cp][pl]) | ((uint)f2bf(lds[2 * cp + 1][pl]) << 16);
        *(uint*)(dst + (size_t)(pix0 + pl) * rowShorts + cp * 2) = u;
    }
}

// zero line at ZOFF, -3.4e38 line at NEGOFF, zero the 8 phase-barrier counters
__global__ void k_zero(uint* __restrict__ rft32, uint* __restrict__ bar) {
    int t = threadIdx.x;
    if (t < 32)        rft32[(ZOFF >> 2) + t] = 0;
    else if (t < 64)   rft32[(NEGOFF >> 2) + (t - 32)] = 0xFF7FFF7Fu;
    else if (t < 72)   bar[t - 64] = 0;
}

// ---------------------------------------------------------------------------
// Flow sampling v7: persistent blocks + phase-aligned slice passes (v6's
// proven locality: FETCH 0.25GB) + restored ILP (v6's failure was a serial
// while-loop: ~650 dependent 400cyc iterations/wave). Each wave owns 24
// pairs; per pass, groups of 4 pairs are prepped into LDS and gathered in a
// fused loop with 4 INDEPENDENT entry streams -> 16 ds_read + 16 global
// loads in flight per iteration. Running max lives in 24 packed-bf16 VGPRs
// (all indices static -- group loop unrolled). Streams shorter than the
// group's trip read a sentinel entry (w=1 @ NEGOFF, L1-resident, neutral).
// Soft global barrier between passes (timing-only; correctness barrier-free).
// ---------------------------------------------------------------------------
__global__ __launch_bounds__(256, 4) void k_sample(const float* __restrict__ flow,
                                                   const char* __restrict__ rftb,
                                                   ushort* __restrict__ xin,
                                                   uint* __restrict__ bar) {
    __shared__ __align__(16) uint pbuf[4][2][4][33][8];  // 33,792 B
    int tid = threadIdx.x;
    int ln = tid & 63;
    int wid = tid >> 6;
    int half = ln >> 5;
    int lk = ln & 31;
    int gw = blockIdx.x * 4 + wid;
    uint laneByte = (uint)(lk * 4);

    if (lk == 0) {                                       // sentinel entries
        #pragma unroll
        for (int s = 0; s < 4; s++) {
            *(int4_*)&pbuf[wid][half][s][32][0] =
                (int4_){(int)NEGOFF, __float_as_int(1.0f), (int)ZOFF, 0};
            *(int4_*)&pbuf[wid][half][s][32][4] = (int4_){(int)ZOFF, 0, (int)ZOFF, 0};
        }
    }
    __syncthreads();

    uint acc[PPW];
    #pragma unroll
    for (int j = 0; j < PPW; j++) acc[j] = 0xFF7FFF7Fu;

    #pragma unroll 1
    for (int pass = 0; pass < 8; pass++) {
        #pragma unroll
        for (int gq = 0; gq < 6; gq++) {
            uint msk[4];
            uint trip = 0;
            #pragma unroll
            for (int s = 0; s < 4; s++) {
                int pj = gw * PPW + gq * 4 + s;
                int pix = pj * 2 + half;
                const float* fp = flow + (size_t)pix * 64 + 2 * lk;
                float gy = fp[0], gx = fp[1];
                float ix = fmaf(gx, 1024.f, 1023.5f);
                float iy = fmaf(gy, 32.f, 31.5f);
                float xf = floorf(ix), yf = floorf(iy);
                float wx = ix - xf, wy = iy - yf;
                int x0 = (int)xf, y0 = (int)yf;
                bool xv0 = (unsigned)x0 < (unsigned)WR;
                bool xv1 = (unsigned)(x0 + 1) < (unsigned)WR;
                bool yv0 = (unsigned)y0 < (unsigned)HR;
                bool yv1 = (unsigned)(y0 + 1) < (unsigned)HR;
                int xc0 = x0 < 0 ? 0 : x0;
                int xc1 = x0 + 1 > WR - 1 ? WR - 1 : x0 + 1;
                int yc0 = y0 < 0 ? 0 : y0;
                int yc1 = y0 + 1 > HR - 1 ? HR - 1 : y0 + 1;
                uint o00 = (xv0 && yv0) ? (uint)(((yc0 << 11) + xc0) << 7) : ZOFF;
                uint o01 = (xv1 && yv0) ? (uint)(((yc0 << 11) + xc1) << 7) : ZOFF;
                uint o10 = (xv0 && yv1) ? (uint)(((yc1 << 11) + xc0) << 7) : ZOFF;
                uint o11 = (xv1 && yv1) ? (uint)(((yc1 << 11) + xc1) << 7) : ZOFF;
                float w00 = (1.f - wy) * (1.f - wx);
                float w01 = (1.f - wy) * wx;
                float w10 = wy * (1.f - wx);
                float w11 = wy * wx;
                *(int4_*)&pbuf[wid][half][s][lk][0] =
                    (int4_){(int)o00, __float_as_int(w00), (int)o01, __float_as_int(w01)};
                *(int4_*)&pbuf[wid][half][s][lk][4] =
                    (int4_){(int)o10, __float_as_int(w10), (int)o11, __float_as_int(w11)};
                int sid = yc0 >> 3;                      // 0..7
                unsigned long long bal = __ballot(sid == pass);
                uint mA = (uint)bal, mB = (uint)(bal >> 32);
                uint cA = (uint)__popc(mA), cB = (uint)__popc(mB);
                uint c = cA > cB ? cA : cB;
                trip = trip > c ? trip : c;
                msk[s] = half ? mB : mA;
            }
            asm volatile("s_waitcnt lgkmcnt(0)" ::: "memory");

            float mLo[4], mHi[4];
            #pragma unroll
            for (int s = 0; s < 4; s++) { mLo[s] = -3.0e38f; mHi[s] = -3.0e38f; }

            for (uint i = 0; i < trip; i++) {
                #pragma unroll
                for (int s = 0; s < 4; s++) {
                    uint m = msk[s];
                    uint idx = m ? (uint)__builtin_ctz(m) : 32u;
                    msk[s] = m & (m - 1u);
                    const uint* e = &pbuf[wid][half][s][idx][0];
                    uint2 e0 = *(const uint2*)(e + 0);   // ds_read_b64 bcast/half
                    uint2 e1 = *(const uint2*)(e + 2);
                    uint2 e2 = *(const uint2*)(e + 4);
                    uint2 e3 = *(const uint2*)(e + 6);
                    uint d0 = *(const uint*)(rftb + (e0.x + laneByte));
                    uint d1 = *(const uint*)(rftb + (e1.x + laneByte));
                    uint d2 = *(const uint*)(rftb + (e2.x + laneByte));
                    uint d3 = *(const uint*)(rftb + (e3.x + laneByte));
                    float W0 = __uint_as_float(e0.y);
                    float W1 = __uint_as_float(e1.y);
                    float W2 = __uint_as_float(e2.y);
                    float W3 = __uint_as_float(e3.y);
                    float vlo = W0 * __uint_as_float(d0 << 16);
                    vlo = fmaf(W1, __uint_as_float(d1 << 16), vlo);
                    vlo = fmaf(W2, __uint_as_float(d2 << 16), vlo);
                    vlo = fmaf(W3, __uint_as_float(d3 << 16), vlo);
                    float vhi = W0 * __uint_as_float(d0 & 0xffff0000u);
                    vhi = fmaf(W1, __uint_as_float(d1 & 0xffff0000u), vhi);
                    vhi = fmaf(W2, __uint_as_float(d2 & 0xffff0000u), vhi);
                    vhi = fmaf(W3, __uint_as_float(d3 & 0xffff0000u), vhi);
                    mLo[s] = fmaxf(mLo[s], vlo);
                    mHi[s] = fmaxf(mHi[s], vhi);
                }
            }
            #pragma unroll
            for (int s = 0; s < 4; s++) {                // merge into packed acc
                uint cur = acc[gq * 4 + s];
                float lo = fmaxf(mLo[s], __uint_as_float(cur << 16));
                float hi = fmaxf(mHi[s], __uint_as_float(cur & 0xffff0000u));
                uint pk;
                asm("v_cvt_pk_bf16_f32 %0, %1, %2" : "=v"(pk) : "v"(lo), "v"(hi));
                acc[gq * 4 + s] = pk;
            }
        }
        if (pass < 7) {                                  // soft global barrier
            __syncthreads();
            if (tid == 0) {
                atomicAdd(&bar[pass], 1u);
                int spins = 0;
                while (__hip_atomic_load(&bar[pass], __ATOMIC_RELAXED,
                                         __HIP_MEMORY_SCOPE_AGENT) < (uint)GRID_S
                       && spins < 3000) {
                    __builtin_amdgcn_s_sleep(2);
                    spins++;
                }
            }
            __syncthreads();
        }
    }

    #pragma unroll
    for (int j = 0; j < PPW; j++) {
        int pix = (gw * PPW + j) * 2 + half;
        __builtin_nontemporal_store(
            acc[j], (uint*)((char*)xin + (size_t)pix * 256 + 128 + lk * 4));
    }
}

// ---------------------------------------------------------------------------
// conv1: implicit-GEMM MFMA, M=64(o), N=192 (180-px half-row + pad), K=1152.
// Input xin bf16 [p][128]. Output res_t f32 [p][64] (BN+ReLU applied).
// ---------------------------------------------------------------------------
__global__ __launch_bounds__(256) void k_mconv1(const ushort* __restrict__ xin,
                                                const ushort* __restrict__ wA,
                                                const float* __restrict__ g,
                                                const float* __restrict__ b,
                                                const float* __restrict__ mn,
                                                const float* __restrict__ vr,
                                                float* __restrict__ res_t) {
    __shared__ __align__(16) ushort xt[3][194][32];
    int tid = threadIdx.x;
    int h = blockIdx.x >> 1, w0 = (blockIdx.x & 1) * 180;
    int wid = tid >> 6, ln = tid & 63;
    f32x4 acc[4][3];
    #pragma unroll
    for (int m = 0; m < 4; m++)
        #pragma unroll
        for (int nf = 0; nf < 3; nf++) acc[m][nf] = (f32x4){0.f, 0.f, 0.f, 0.f};

    for (int c = 0; c < 4; c++) {
        __syncthreads();
        for (int i = tid; i < 2184; i += 256) {          // 546 slots x 4 quads
            int q = i & 3, s = i >> 2;
            int r = s / 182, pw = s - r * 182;
            int gh = h + r - 1;
            int gw = w0 + pw - 1;
            if (gw < 0) gw += WW;
            if (gw >= WW) gw -= WW;
            int4_ val = {0, 0, 0, 0};
            if ((unsigned)gh < (unsigned)HH)
                val = *(const int4_*)(xin + ((size_t)(gh * WW + gw) * 128 + c * 32 + q * 8));
            *(int4_*)&xt[r][pw][(q ^ (pw & 3)) * 8] = val;
        }
        __syncthreads();
        #pragma unroll
        for (int tap = 0; tap < 9; tap++) {
            int dh = tap / 3, dw = tap % 3;
            short8 aF[4];
            #pragma unroll
            for (int m = 0; m < 4; m++)
                aF[m] = *(const short8*)(wA + (size_t)(((c * 9 + tap) * 4 + m) * 64 + ln) * 8);
            short8 bF[3];
            #pragma unroll
            for (int nf = 0; nf < 3; nf++) {
                int pw = wid * 48 + nf * 16 + (ln & 15) + dw;
                bF[nf] = *(const short8*)&xt[dh][pw][((((ln >> 4) & 3)) ^ (pw & 3)) * 8];
            }
            #pragma unroll
            for (int m = 0; m < 4; m++)
                #pragma unroll
                for (int nf = 0; nf < 3; nf++)
                    acc[m][nf] = __builtin_amdgcn_mfma_f32_16x16x32_bf16(aF[m], bF[nf], acc[m][nf], 0, 0, 0);
        }
    }
    // epilogue: BN + ReLU -> res_t[p][o]
    #pragma unroll
    for (int m = 0; m < 4; m++) {
        #pragma unroll
        for (int reg = 0; reg < 4; reg++) {
            int o = m * 16 + ((ln >> 4) & 3) * 4 + reg;
            float sc = g[o] * rsqrtf(vr[o] + 1e-5f);
            float bi = b[o] - mn[o] * sc;
            #pragma unroll
            for (int nf = 0; nf < 3; nf++) {
                int n = wid * 48 + nf * 16 + (ln & 15);
                if (n < 180) {
                    int P = h * WW + w0 + n;
                    float v = fmaf(acc[m][nf][reg], sc, bi);
                    res_t[(size_t)P * 64 + o] = fmaxf(v, 0.f);
                }
            }
        }
    }
}

// ---------------------------------------------------------------------------
// conv2: same GEMM (K=576) on res_t (f32 -> bf16 staged), BN + channel
// softmax + final out = polar + res*att.
// ---------------------------------------------------------------------------
__global__ __launch_bounds__(256) void k_mconv2(const float* __restrict__ res_t,
                                                const float* __restrict__ polar,
                                                const ushort* __restrict__ wA,
                                                const float* __restrict__ g,
                                                const float* __restrict__ b,
                                                const float* __restrict__ mn,
                                                const float* __restrict__ vr,
                                                float* __restrict__ out) {
    __shared__ __align__(16) ushort xt[3][194][32];
    int tid = threadIdx.x;
    int h = blockIdx.x >> 1, w0 = (blockIdx.x & 1) * 180;
    int wid = tid >> 6, ln = tid & 63;
    f32x4 acc[4][3];
    #pragma unroll
    for (int m = 0; m < 4; m++)
        #pragma unroll
        for (int nf = 0; nf < 3; nf++) acc[m][nf] = (f32x4){0.f, 0.f, 0.f, 0.f};

    for (int c = 0; c < 2; c++) {
        __syncthreads();
        for (int i = tid; i < 2184; i += 256) {
            int q = i & 3, s = i >> 2;
            int r = s / 182, pw = s - r * 182;
            int gh = h + r - 1;
            int gw = w0 + pw - 1;
            if (gw < 0) gw += WW;
            if (gw >= WW) gw -= WW;
            int4_ val = {0, 0, 0, 0};
            if ((unsigned)gh < (unsigned)HH) {
                const float* src = res_t + ((size_t)(gh * WW + gw) * 64 + c * 32 + q * 8);
                f32x4 va = *(const f32x4*)src;
                f32x4 vb = *(const f32x4*)(src + 4);
                uint u0, u1, u2, u3;
                asm("v_cvt_pk_bf16_f32 %0, %1, %2" : "=v"(u0) : "v"(va[0]), "v"(va[1]));
                asm("v_cvt_pk_bf16_f32 %0, %1, %2" : "=v"(u1) : "v"(va[2]), "v"(va[3]));
                asm("v_cvt_pk_bf16_f32 %0, %1, %2" : "=v"(u2) : "v"(vb[0]), "v"(vb[1]));
                asm("v_cvt_pk_bf16_f32 %0, %1, %2" : "=v"(u3) : "v"(vb[2]), "v"(vb[3]));
                val = (int4_){(int)u0, (int)u1, (int)u2, (int)u3};
            }
            *(int4_*)&xt[r][pw][(q ^ (pw & 3)) * 8] = val;
        }
        __syncthreads();
        #pragma unroll
        for (int tap = 0; tap < 9; tap++) {
            int dh = tap / 3, dw = tap % 3;
            short8 aF[4];
            #pragma unroll
            for (int m = 0; m < 4; m++)
                aF[m] = *(const short8*)(wA + (size_t)(((c * 9 + tap) * 4 + m) * 64 + ln) * 8);
            short8 bF[3];
            #pragma unroll
            for (int nf = 0; nf < 3; nf++) {
                int pw = wid * 48 + nf * 16 + (ln & 15) + dw;
                bF[nf] = *(const short8*)&xt[dh][pw][((((ln >> 4) & 3)) ^ (pw & 3)) * 8];
            }
            #pragma unroll
            for (int m = 0; m < 4; m++)
                #pragma unroll
                for (int nf = 0; nf < 3; nf++)
                    acc[m][nf] = __builtin_amdgcn_mfma_f32_16x16x32_bf16(aF[m], bF[nf], acc[m][nf], 0, 0, 0);
        }
    }
    // epilogue: BN -> softmax over 64 channels -> out = polar + res*att
    #pragma unroll
    for (int m = 0; m < 4; m++) {
        #pragma unroll
        for (int reg = 0; reg < 4; reg++) {
            int o = m * 16 + ((ln >> 4) & 3) * 4 + reg;
            float sc = g[o] * rsqrtf(vr[o] + 1e-5f);
            float bi = b[o] - mn[o] * sc;
            #pragma unroll
            for (int nf = 0; nf < 3; nf++)
                acc[m][nf][reg] = fmaf(acc[m][nf][reg], sc, bi);
        }
    }
    #pragma unroll
    for (int nf = 0; nf < 3; nf++) {
        float mx = -3.0e38f;
        #pragma unroll
        for (int m = 0; m < 4; m++)
            #pragma unroll
            for (int reg = 0; reg < 4; reg++) mx = fmaxf(mx, acc[m][nf][reg]);
        mx = fmaxf(mx, __shfl_xor(mx, 16));
        mx = fmaxf(mx, __shfl_xor(mx, 32));
        float s = 0.f;
        #pragma unroll
        for (int m = 0; m < 4; m++)
            #pragma unroll
            for (int reg = 0; reg < 4; reg++) {
                float e = __expf(acc[m][nf][reg] - mx);
                acc[m][nf][reg] = e;
                s += e;
            }
        s += __shfl_xor(s, 16);
        s += __shfl_xor(s, 32);
        float rinv = 1.f / s;
        int n = wid * 48 + nf * 16 + (ln & 15);
        if (n < 180) {
            int P = h * WW + w0 + n;
            #pragma unroll
            for (int m = 0; m < 4; m++)
                #pragma unroll
                for (int reg = 0; reg < 4; reg++) {
                    int o = m * 16 + ((ln >> 4) & 3) * 4 + reg;
                    float att = acc[m][nf][reg] * rinv;
                    out[(size_t)o * NPIX + P] =
                        fmaf(res_t[(size_t)P * 64 + o], att, polar[(size_t)o * NPIX + P]);
                }
        }
    }
}

// ---------------------------------------------------------------------------
extern "C" void kernel_launch(void* const* d_in, const int* in_sizes, int n_in,
                              void* d_out, int out_size, void* d_ws, size_t ws_size,
                              hipStream_t stream) {
    const float* flow  = (const float*)d_in[0];
    const float* polar = (const float*)d_in[1];
    const float* rf    = (const float*)d_in[2];
    const float* fw    = (const float*)d_in[3];
    const float* fg    = (const float*)d_in[4];
    const float* fb    = (const float*)d_in[5];
    const float* fm    = (const float*)d_in[6];
    const float* fv    = (const float*)d_in[7];
    const float* aw    = (const float*)d_in[8];
    const float* ag    = (const float*)d_in[9];
    const float* ab    = (const float*)d_in[10];
    const float* am    = (const float*)d_in[11];
    const float* av    = (const float*)d_in[12];
    float* out = (float*)d_out;

    char* wsb = (char*)d_ws;
    ushort* xin   = (ushort*)wsb;                         // [NPIX][128] bf16 = 44,236,800 B
    ushort* rft   = (ushort*)(wsb + 44236800);            // [RFNPIX][64] bf16 + sentinel lines
    float*  res_t = (float*)(wsb + 61014272);             // [NPIX][64] f32 = 44,236,800 B
    ushort* wA1   = (ushort*)(wsb + 105251072);           // 147,456 B
    ushort* wA2   = wA1 + 73728;                          // 73,728 B
    uint*   bar   = (uint*)(wsb + 105472256);             // 8 phase counters

    k_wprep<<<432, 256, 0, stream>>>(fw, aw, wA1, wA2);
    k_tr<<<NPIX / 64, 256, 0, stream>>>(polar, xin, NPIX, 128);
    k_tr<<<RFNPIX / 64, 256, 0, stream>>>(rf, rft, RFNPIX, 64);
    k_zero<<<1, 128, 0, stream>>>((uint*)rft, bar);
    k_sample<<<GRID_S, 256, 0, stream>>>(flow, (const char*)rft, xin, bar);
    k_mconv1<<<960, 256, 0, stream>>>(xin, wA1, fg, fb, fm, fv, res_t);
    k_mconv2<<<960, 256, 0, stream>>>(res_t, polar, wA2, ag, ab, am, av, out);
}

// Round 10
// 433.916 us; speedup vs baseline: 2.9804x; 2.9804x over previous
//
#include <hip/hip_runtime.h>
#include <math.h>

#define CCH 64
#define HH 480
#define WW 360
#define KK 32
#define HR 64
#define WR 2048
#define NPIX (HH*WW)            // 172800
#define RFNPIX (HR*WR)          // 131072
#define ZOFF 16777216u          // byte offset of zero line in rfT16
#define NEGOFF 16777344u        // byte offset of -3.4e38 sentinel line

typedef __attribute__((ext_vector_type(8))) short short8;
typedef __attribute__((ext_vector_type(4))) float f32x4;
typedef __attribute__((ext_vector_type(4))) int  int4_;

__device__ __forceinline__ ushort f2bf(float f) {        // RTN f32->bf16
    uint u = __float_as_uint(f);
    return (ushort)((u + 0x7fffu + ((u >> 16) & 1u)) >> 16);
}

// ---------------------------------------------------------------------------
// Weight prep: pack conv weights into MFMA A-fragment order, bf16.
// ---------------------------------------------------------------------------
__global__ __launch_bounds__(256) void k_wprep(const float* __restrict__ fw,
                                               const float* __restrict__ aw,
                                               ushort* __restrict__ wA1,
                                               ushort* __restrict__ wA2) {
    int t = blockIdx.x * 256 + threadIdx.x;
    if (t < 73728) {                                   // conv1: 4 chunks (128 ci)
        int j = t & 7, ln = (t >> 3) & 63, Mf = (t >> 9) & 3, rem = t >> 11;
        int tap = rem % 9, c = rem / 9;
        int o = Mf * 16 + (ln & 15);
        int ci = c * 32 + ((ln >> 4) & 3) * 8 + j;
        wA1[t] = f2bf(fw[(o * 128 + ci) * 9 + tap]);
    } else if (t < 73728 + 36864) {                    // conv2: 2 chunks (64 ci)
        int i = t - 73728;
        int j = i & 7, ln = (i >> 3) & 63, Mf = (i >> 9) & 3, rem = i >> 11;
        int tap = rem % 9, c = rem / 9;
        int o = Mf * 16 + (ln & 15);
        int ci = c * 32 + ((ln >> 4) & 3) * 8 + j;
        wA2[i] = f2bf(aw[(o * 64 + ci) * 9 + tap]);
    }
}

// ---------------------------------------------------------------------------
// Transpose f32 [64][npix] -> bf16 channel-last [npix][rowShorts] (cols 0..63)
// ---------------------------------------------------------------------------
__global__ __launch_bounds__(256) void k_tr(const float* __restrict__ src,
                                            ushort* __restrict__ dst,
                                            int npix, int rowShorts) {
    __shared__ float lds[64][65];
    int t = threadIdx.x;
    int pix0 = blockIdx.x * 64;
    int lx = t & 63, ty = t >> 6;
    #pragma unroll
    for (int cc = 0; cc < 64; cc += 4) {
        int c = cc + ty;
        lds[c][lx] = src[(size_t)c * npix + pix0 + lx];
    }
    __syncthreads();
    int cp = t & 31, po = t >> 5;        // cp = channel pair, po = pixel offset
    #pragma unroll
    for (int pl = po; pl < 64; pl += 8) {
        uint u = (uint)f2bf(lds[2 * cp][pl]) | ((uint)f2bf(lds[2 * cp + 1][pl]) << 16);
        *(uint*)(dst + (size_t)(pix0 + pl) * rowShorts + cp * 2) = u;
    }
}

// zero line at ZOFF, -3.4e38 (bf16 pair pattern) line at NEGOFF
__global__ void k_zero(uint* __restrict__ rft32) {
    int t = threadIdx.x;
    if (t < 32)       rft32[(ZOFF >> 2) + t] = 0;
    else if (t < 64)  rft32[(NEGOFF >> 2) + (t - 32)] = 0xFF7FFF7Fu;
}

// ---------------------------------------------------------------------------
// Flow sampling v8 = v5 (proven 267us) + XCD-rotated slice order.
// 2 pixels per wave; per-lane prep of one (pixel,k) -> 4 corner byte-offsets
// + 4 weights in LDS, counting-sorted per half-wave by slice id (sid =
// clamped_y0>>3; slice = 9 rows = 2.25MB). Gather runs the 8 slice passes in
// order (pass + (blockIdx&7)) & 7: blocks dispatch round-robin over the 8
// XCDs, so co-resident blocks on one XCD share the same rotation class and
// adjacent progress -> per-XCD live slice window shrinks from 8 slices to
// ~2-3 (~fits the 4MB per-XCD L2) with ZERO sync cost. (v6/v7's explicit
// global barrier achieved FETCH 0.25GB but cost 4x wall time -- reverted.)
// Wave trip per pass = max(cntA,cntB); surplus iters read a dummy entry
// (w00=1 at NEGOFF sentinel = -3.4e38, neutral in max, L1-resident).
// ---------------------------------------------------------------------------
__global__ __launch_bounds__(256) void k_sample(const float* __restrict__ flow,
                                                const char* __restrict__ rftb,
                                                ushort* __restrict__ xin) {
    __shared__ __align__(16) uint pbuf[4][2][33][8];   // [wave][half][entry][(off,w)x4]
    int tid = threadIdx.x;
    int ln = tid & 63;
    int wid = tid >> 6;
    int half = ln >> 5;
    int gwave = blockIdx.x * 4 + wid;

    // ---- prep (per-lane: one (pixel,k)) ----
    int k = ln & 31;
    int pix = gwave * 2 + half;
    const float* fp = flow + (size_t)pix * 64 + 2 * k;
    float gy = fp[0], gx = fp[1];
    float ix = fmaf(gx, 1024.f, 1023.5f);
    float iy = fmaf(gy, 32.f, 31.5f);
    float xf = floorf(ix), yf = floorf(iy);
    float wx = ix - xf, wy = iy - yf;
    int x0 = (int)xf, y0 = (int)yf;
    bool xv0 = (unsigned)x0 < (unsigned)WR;
    bool xv1 = (unsigned)(x0 + 1) < (unsigned)WR;
    bool yv0 = (unsigned)y0 < (unsigned)HR;
    bool yv1 = (unsigned)(y0 + 1) < (unsigned)HR;
    int xc0 = x0 < 0 ? 0 : x0;
    int xc1 = x0 + 1 > WR - 1 ? WR - 1 : x0 + 1;
    int yc0 = y0 < 0 ? 0 : y0;
    int yc1 = y0 + 1 > HR - 1 ? HR - 1 : y0 + 1;
    uint o00 = (xv0 && yv0) ? (uint)(((yc0 << 11) + xc0) << 7) : ZOFF;
    uint o01 = (xv1 && yv0) ? (uint)(((yc0 << 11) + xc1) << 7) : ZOFF;
    uint o10 = (xv0 && yv1) ? (uint)(((yc1 << 11) + xc0) << 7) : ZOFF;
    uint o11 = (xv1 && yv1) ? (uint)(((yc1 << 11) + xc1) << 7) : ZOFF;
    float w00 = (1.f - wy) * (1.f - wx);
    float w01 = (1.f - wy) * wx;
    float w10 = wy * (1.f - wx);
    float w11 = wy * wx;

    // ---- counting sort by slice id (8 buckets) within each half-wave ----
    int sid = yc0 >> 3;                                  // 0..7
    unsigned long long hm = half ? 0xFFFFFFFF00000000ull : 0x00000000FFFFFFFFull;
    unsigned long long lower = (1ull << ln) - 1ull;
    int cnts[8], starts[8];
    int mystart = 0, rank = 0, acc = 0;
    #pragma unroll
    for (int s = 0; s < 8; s++) {
        unsigned long long bal = __ballot(sid == s);
        int c = __popcll(bal & hm);
        cnts[s] = c;
        starts[s] = acc;
        if (sid == s) {
            mystart = acc;
            rank = __popcll(bal & hm & lower);
        }
        acc += c;
    }
    int pos = mystart + rank;
    *(int4_*)&pbuf[wid][half][pos][0] =
        (int4_){(int)o00, __float_as_int(w00), (int)o01, __float_as_int(w01)};
    *(int4_*)&pbuf[wid][half][pos][4] =
        (int4_){(int)o10, __float_as_int(w10), (int)o11, __float_as_int(w11)};
    if ((ln & 31) == 0) {                                // dummy entry at pos 32
        *(int4_*)&pbuf[wid][half][32][0] =
            (int4_){(int)NEGOFF, __float_as_int(1.0f), (int)ZOFF, 0};
        *(int4_*)&pbuf[wid][half][32][4] = (int4_){(int)ZOFF, 0, (int)ZOFF, 0};
    }
    __syncthreads();

    uint laneByte = (uint)((ln & 31) * 4);
    const uint* pb = &pbuf[wid][half][0][0];
    float mLo = -3.0e38f, mHi = -3.0e38f;
    int rot = (int)(blockIdx.x & 7);                     // XCD rotation class

    // ---- gather: 8 slice passes over sorted buckets, XCD-rotated order ----
    #pragma unroll
    for (int p = 0; p < 8; p++) {
        int s = (p + rot) & 7;
        int myCnt = cnts[s];
        int myStart = starts[s];
        int cA = __builtin_amdgcn_readlane(myCnt, 0);
        int cB = __builtin_amdgcn_readlane(myCnt, 32);
        int trip = cA > cB ? cA : cB;
        for (int i = 0; i < trip; i++) {
            int idx = (i < myCnt) ? (myStart + i) : 32;
            const uint* e = pb + idx * 8;
            uint2 e0 = *(const uint2*)(e + 0);           // ds_read_b64, bcast/half
            uint2 e1 = *(const uint2*)(e + 2);
            uint2 e2 = *(const uint2*)(e + 4);
            uint2 e3 = *(const uint2*)(e + 6);
            uint d0 = *(const uint*)(rftb + (e0.x + laneByte));
            uint d1 = *(const uint*)(rftb + (e1.x + laneByte));
            uint d2 = *(const uint*)(rftb + (e2.x + laneByte));
            uint d3 = *(const uint*)(rftb + (e3.x + laneByte));
            float W0 = __uint_as_float(e0.y);
            float W1 = __uint_as_float(e1.y);
            float W2 = __uint_as_float(e2.y);
            float W3 = __uint_as_float(e3.y);

            float vlo = W0 * __uint_as_float(d0 << 16);
            vlo = fmaf(W1, __uint_as_float(d1 << 16), vlo);
            vlo = fmaf(W2, __uint_as_float(d2 << 16), vlo);
            vlo = fmaf(W3, __uint_as_float(d3 << 16), vlo);
            float vhi = W0 * __uint_as_float(d0 & 0xffff0000u);
            vhi = fmaf(W1, __uint_as_float(d1 & 0xffff0000u), vhi);
            vhi = fmaf(W2, __uint_as_float(d2 & 0xffff0000u), vhi);
            vhi = fmaf(W3, __uint_as_float(d3 & 0xffff0000u), vhi);
            mLo = fmaxf(mLo, vlo);
            mHi = fmaxf(mHi, vhi);
        }
    }

    uint outw;
    asm("v_cvt_pk_bf16_f32 %0, %1, %2" : "=v"(outw) : "v"(mLo), "v"(mHi));
    *(uint*)((char*)xin + (size_t)pix * 256 + 128 + (ln & 31) * 4) = outw;
}

// ---------------------------------------------------------------------------
// conv1: implicit-GEMM MFMA, M=64(o), N=192 (180-px half-row + pad), K=1152.
// Input xin bf16 [p][128]. Output res_t f32 [p][64] (BN+ReLU applied).
// ---------------------------------------------------------------------------
__global__ __launch_bounds__(256) void k_mconv1(const ushort* __restrict__ xin,
                                                const ushort* __restrict__ wA,
                                                const float* __restrict__ g,
                                                const float* __restrict__ b,
                                                const float* __restrict__ mn,
                                                const float* __restrict__ vr,
                                                float* __restrict__ res_t) {
    __shared__ __align__(16) ushort xt[3][194][32];
    int tid = threadIdx.x;
    int h = blockIdx.x >> 1, w0 = (blockIdx.x & 1) * 180;
    int wid = tid >> 6, ln = tid & 63;
    f32x4 acc[4][3];
    #pragma unroll
    for (int m = 0; m < 4; m++)
        #pragma unroll
        for (int nf = 0; nf < 3; nf++) acc[m][nf] = (f32x4){0.f, 0.f, 0.f, 0.f};

    for (int c = 0; c < 4; c++) {
        __syncthreads();
        for (int i = tid; i < 2184; i += 256) {          // 546 slots x 4 quads
            int q = i & 3, s = i >> 2;
            int r = s / 182, pw = s - r * 182;
            int gh = h + r - 1;
            int gw = w0 + pw - 1;
            if (gw < 0) gw += WW;
            if (gw >= WW) gw -= WW;
            int4_ val = {0, 0, 0, 0};
            if ((unsigned)gh < (unsigned)HH)
                val = *(const int4_*)(xin + ((size_t)(gh * WW + gw) * 128 + c * 32 + q * 8));
            *(int4_*)&xt[r][pw][(q ^ (pw & 3)) * 8] = val;
        }
        __syncthreads();
        #pragma unroll
        for (int tap = 0; tap < 9; tap++) {
            int dh = tap / 3, dw = tap % 3;
            short8 aF[4];
            #pragma unroll
            for (int m = 0; m < 4; m++)
                aF[m] = *(const short8*)(wA + (size_t)(((c * 9 + tap) * 4 + m) * 64 + ln) * 8);
            short8 bF[3];
            #pragma unroll
            for (int nf = 0; nf < 3; nf++) {
                int pw = wid * 48 + nf * 16 + (ln & 15) + dw;
                bF[nf] = *(const short8*)&xt[dh][pw][((((ln >> 4) & 3)) ^ (pw & 3)) * 8];
            }
            #pragma unroll
            for (int m = 0; m < 4; m++)
                #pragma unroll
                for (int nf = 0; nf < 3; nf++)
                    acc[m][nf] = __builtin_amdgcn_mfma_f32_16x16x32_bf16(aF[m], bF[nf], acc[m][nf], 0, 0, 0);
        }
    }
    // epilogue: BN + ReLU -> res_t[p][o]
    #pragma unroll
    for (int m = 0; m < 4; m++) {
        #pragma unroll
        for (int reg = 0; reg < 4; reg++) {
            int o = m * 16 + ((ln >> 4) & 3) * 4 + reg;
            float sc = g[o] * rsqrtf(vr[o] + 1e-5f);
            float bi = b[o] - mn[o] * sc;
            #pragma unroll
            for (int nf = 0; nf < 3; nf++) {
                int n = wid * 48 + nf * 16 + (ln & 15);
                if (n < 180) {
                    int P = h * WW + w0 + n;
                    float v = fmaf(acc[m][nf][reg], sc, bi);
                    res_t[(size_t)P * 64 + o] = fmaxf(v, 0.f);
                }
            }
        }
    }
}

// ---------------------------------------------------------------------------
// conv2: same GEMM (K=576) on res_t (f32 -> bf16 staged), BN + channel
// softmax + final out = polar + res*att.
// ---------------------------------------------------------------------------
__global__ __launch_bounds__(256) void k_mconv2(const float* __restrict__ res_t,
                                                const float* __restrict__ polar,
                                                const ushort* __restrict__ wA,
                                                const float* __restrict__ g,
                                                const float* __restrict__ b,
                                                const float* __restrict__ mn,
                                                const float* __restrict__ vr,
                                                float* __restrict__ out) {
    __shared__ __align__(16) ushort xt[3][194][32];
    int tid = threadIdx.x;
    int h = blockIdx.x >> 1, w0 = (blockIdx.x & 1) * 180;
    int wid = tid >> 6, ln = tid & 63;
    f32x4 acc[4][3];
    #pragma unroll
    for (int m = 0; m < 4; m++)
        #pragma unroll
        for (int nf = 0; nf < 3; nf++) acc[m][nf] = (f32x4){0.f, 0.f, 0.f, 0.f};

    for (int c = 0; c < 2; c++) {
        __syncthreads();
        for (int i = tid; i < 2184; i += 256) {
            int q = i & 3, s = i >> 2;
            int r = s / 182, pw = s - r * 182;
            int gh = h + r - 1;
            int gw = w0 + pw - 1;
            if (gw < 0) gw += WW;
            if (gw >= WW) gw -= WW;
            int4_ val = {0, 0, 0, 0};
            if ((unsigned)gh < (unsigned)HH) {
                const float* src = res_t + ((size_t)(gh * WW + gw) * 64 + c * 32 + q * 8);
                f32x4 va = *(const f32x4*)src;
                f32x4 vb = *(const f32x4*)(src + 4);
                uint u0, u1, u2, u3;
                asm("v_cvt_pk_bf16_f32 %0, %1, %2" : "=v"(u0) : "v"(va[0]), "v"(va[1]));
                asm("v_cvt_pk_bf16_f32 %0, %1, %2" : "=v"(u1) : "v"(va[2]), "v"(va[3]));
                asm("v_cvt_pk_bf16_f32 %0, %1, %2" : "=v"(u2) : "v"(vb[0]), "v"(vb[1]));
                asm("v_cvt_pk_bf16_f32 %0, %1, %2" : "=v"(u3) : "v"(vb[2]), "v"(vb[3]));
                val = (int4_){(int)u0, (int)u1, (int)u2, (int)u3};
            }
            *(int4_*)&xt[r][pw][(q ^ (pw & 3)) * 8] = val;
        }
        __syncthreads();
        #pragma unroll
        for (int tap = 0; tap < 9; tap++) {
            int dh = tap / 3, dw = tap % 3;
            short8 aF[4];
            #pragma unroll
            for (int m = 0; m < 4; m++)
                aF[m] = *(const short8*)(wA + (size_t)(((c * 9 + tap) * 4 + m) * 64 + ln) * 8);
            short8 bF[3];
            #pragma unroll
            for (int nf = 0; nf < 3; nf++) {
                int pw = wid * 48 + nf * 16 + (ln & 15) + dw;
                bF[nf] = *(const short8*)&xt[dh][pw][((((ln >> 4) & 3)) ^ (pw & 3)) * 8];
            }
            #pragma unroll
            for (int m = 0; m < 4; m++)
                #pragma unroll
                for (int nf = 0; nf < 3; nf++)
                    acc[m][nf] = __builtin_amdgcn_mfma_f32_16x16x32_bf16(aF[m], bF[nf], acc[m][nf], 0, 0, 0);
        }
    }
    // epilogue: BN -> softmax over 64 channels -> out = polar + res*att
    #pragma unroll
    for (int m = 0; m < 4; m++) {
        #pragma unroll
        for (int reg = 0; reg < 4; reg++) {
            int o = m * 16 + ((ln >> 4) & 3) * 4 + reg;
            float sc = g[o] * rsqrtf(vr[o] + 1e-5f);
            float bi = b[o] - mn[o] * sc;
            #pragma unroll
            for (int nf = 0; nf < 3; nf++)
                acc[m][nf][reg] = fmaf(acc[m][nf][reg], sc, bi);
        }
    }
    #pragma unroll
    for (int nf = 0; nf < 3; nf++) {
        float mx = -3.0e38f;
        #pragma unroll
        for (int m = 0; m < 4; m++)
            #pragma unroll
            for (int reg = 0; reg < 4; reg++) mx = fmaxf(mx, acc[m][nf][reg]);
        mx = fmaxf(mx, __shfl_xor(mx, 16));
        mx = fmaxf(mx, __shfl_xor(mx, 32));
        float s = 0.f;
        #pragma unroll
        for (int m = 0; m < 4; m++)
            #pragma unroll
            for (int reg = 0; reg < 4; reg++) {
                float e = __expf(acc[m][nf][reg] - mx);
                acc[m][nf][reg] = e;
                s += e;
            }
        s += __shfl_xor(s, 16);
        s += __shfl_xor(s, 32);
        float rinv = 1.f / s;
        int n = wid * 48 + nf * 16 + (ln & 15);
        if (n < 180) {
            int P = h * WW + w0 + n;
            #pragma unroll
            for (int m = 0; m < 4; m++)
                #pragma unroll
                for (int reg = 0; reg < 4; reg++) {
                    int o = m * 16 + ((ln >> 4) & 3) * 4 + reg;
                    float att = acc[m][nf][reg] * rinv;
                    out[(size_t)o * NPIX + P] =
                        fmaf(res_t[(size_t)P * 64 + o], att, polar[(size_t)o * NPIX + P]);
                }
        }
    }
}

// ---------------------------------------------------------------------------
extern "C" void kernel_launch(void* const* d_in, const int* in_sizes, int n_in,
                              void* d_out, int out_size, void* d_ws, size_t ws_size,
                              hipStream_t stream) {
    const float* flow  = (const float*)d_in[0];
    const float* polar = (const float*)d_in[1];
    const float* rf    = (const float*)d_in[2];
    const float* fw    = (const float*)d_in[3];
    const float* fg    = (const float*)d_in[4];
    const float* fb    = (const float*)d_in[5];
    const float* fm    = (const float*)d_in[6];
    const float* fv    = (const float*)d_in[7];
    const float* aw    = (const float*)d_in[8];
    const float* ag    = (const float*)d_in[9];
    const float* ab    = (const float*)d_in[10];
    const float* am    = (const float*)d_in[11];
    const float* av    = (const float*)d_in[12];
    float* out = (float*)d_out;

    char* wsb = (char*)d_ws;
    ushort* xin   = (ushort*)wsb;                         // [NPIX][128] bf16 = 44,236,800 B
    ushort* rft   = (ushort*)(wsb + 44236800);            // [RFNPIX][64] bf16 + sentinel lines
    float*  res_t = (float*)(wsb + 61014272);             // [NPIX][64] f32 = 44,236,800 B
    ushort* wA1   = (ushort*)(wsb + 105251072);           // 147,456 B
    ushort* wA2   = wA1 + 73728;                          // 73,728 B

    k_wprep<<<432, 256, 0, stream>>>(fw, aw, wA1, wA2);
    k_tr<<<NPIX / 64, 256, 0, stream>>>(polar, xin, NPIX, 128);
    k_tr<<<RFNPIX / 64, 256, 0, stream>>>(rf, rft, RFNPIX, 64);
    k_zero<<<1, 64, 0, stream>>>((uint*)rft);
    k_sample<<<NPIX / 8, 256, 0, stream>>>(flow, (const char*)rft, xin);
    k_mconv1<<<960, 256, 0, stream>>>(xin, wA1, fg, fb, fm, fv, res_t);
    k_mconv2<<<960, 256, 0, stream>>>(res_t, polar, wA2, ag, ab, am, av, out);
}

// Round 12
// 365.103 us; speedup vs baseline: 3.5421x; 1.1885x over previous
//
#include <hip/hip_runtime.h>
#include <math.h>

#define CCH 64
#define HH 480
#define WW 360
#define KK 32
#define HR 64
#define WR 2048
#define NPIX (HH*WW)            // 172800
#define RFNPIX (HR*WR)          // 131072
#define ZOFF 16777216u          // byte offset of zero line in rfT16
#define NEGOFF 16777344u        // byte offset of -3.4e38 sentinel line

typedef __attribute__((ext_vector_type(8))) short short8;
typedef __attribute__((ext_vector_type(4))) float f32x4;
typedef __attribute__((ext_vector_type(4))) int  int4_;

__device__ __forceinline__ ushort f2bf(float f) {        // RTN f32->bf16
    uint u = __float_as_uint(f);
    return (ushort)((u + 0x7fffu + ((u >> 16) & 1u)) >> 16);
}

// ---------------------------------------------------------------------------
// Weight prep: pack conv weights into MFMA A-fragment order, bf16.
// ---------------------------------------------------------------------------
__global__ __launch_bounds__(256) void k_wprep(const float* __restrict__ fw,
                                               const float* __restrict__ aw,
                                               ushort* __restrict__ wA1,
                                               ushort* __restrict__ wA2) {
    int t = blockIdx.x * 256 + threadIdx.x;
    if (t < 73728) {                                   // conv1: 4 chunks (128 ci)
        int j = t & 7, ln = (t >> 3) & 63, Mf = (t >> 9) & 3, rem = t >> 11;
        int tap = rem % 9, c = rem / 9;
        int o = Mf * 16 + (ln & 15);
        int ci = c * 32 + ((ln >> 4) & 3) * 8 + j;
        wA1[t] = f2bf(fw[(o * 128 + ci) * 9 + tap]);
    } else if (t < 73728 + 36864) {                    // conv2: 2 chunks (64 ci)
        int i = t - 73728;
        int j = i & 7, ln = (i >> 3) & 63, Mf = (i >> 9) & 3, rem = i >> 11;
        int tap = rem % 9, c = rem / 9;
        int o = Mf * 16 + (ln & 15);
        int ci = c * 32 + ((ln >> 4) & 3) * 8 + j;
        wA2[i] = f2bf(aw[(o * 64 + ci) * 9 + tap]);
    }
}

// ---------------------------------------------------------------------------
// Transpose f32 [64][npix] -> bf16 channel-last [npix][rowShorts] (cols 0..63)
// ---------------------------------------------------------------------------
__global__ __launch_bounds__(256) void k_tr(const float* __restrict__ src,
                                            ushort* __restrict__ dst,
                                            int npix, int rowShorts) {
    __shared__ float lds[64][65];
    int t = threadIdx.x;
    int pix0 = blockIdx.x * 64;
    int lx = t & 63, ty = t >> 6;
    #pragma unroll
    for (int cc = 0; cc < 64; cc += 4) {
        int c = cc + ty;
        lds[c][lx] = src[(size_t)c * npix + pix0 + lx];
    }
    __syncthreads();
    int cp = t & 31, po = t >> 5;        // cp = channel pair, po = pixel offset
    #pragma unroll
    for (int pl = po; pl < 64; pl += 8) {
        uint u = (uint)f2bf(lds[2 * cp][pl]) | ((uint)f2bf(lds[2 * cp + 1][pl]) << 16);
        *(uint*)(dst + (size_t)(pix0 + pl) * rowShorts + cp * 2) = u;
    }
}

// zero line at ZOFF, -3.4e38 (bf16 pair pattern) line at NEGOFF
__global__ void k_zero(uint* __restrict__ rft32) {
    int t = threadIdx.x;
    if (t < 32)       rft32[(ZOFF >> 2) + t] = 0;
    else if (t < 64)  rft32[(NEGOFF >> 2) + (t - 32)] = 0xFF7FFF7Fu;
}

// ---------------------------------------------------------------------------
// Flow sampling v9: v5's fast structure, split into TWO sequential dispatches
// (sel=0: table rows [0,32); sel=1: rows [32,64)). The kernel-launch boundary
// is a FREE global phase barrier: during each dispatch the live table
// footprint is 8.4 MB (vs 16.8), so per-XCD L2 hit rate rises, cutting the
// ~3.75 TB/s-pinned miss stream's bytes. Running max is merged through xin
// (bf16; max is monotone, <=1 ulp double-rounding). Prep runs per dispatch
// (cheap: ~90cyc/wave) but the 8-bucket sort is replaced by a single 2-ballot
// partition (in-range entries compacted to pbuf front). Wave trip =
// max(cntA,cntB); surplus iters of the shorter half read a dummy entry
// (w00=1 at NEGOFF = -3.4e38, neutral in max, L1-resident). Flow loads are
// nontemporal to reduce L2 pollution of the table window.
// ---------------------------------------------------------------------------
__global__ __launch_bounds__(256) void k_sample(const float* __restrict__ flow,
                                                const char* __restrict__ rftb,
                                                ushort* __restrict__ xin,
                                                int sel, int mergePrev) {
    __shared__ __align__(16) uint pbuf[4][2][33][8];   // [wave][half][entry][(off,w)x4]
    int tid = threadIdx.x;
    int ln = tid & 63;
    int wid = tid >> 6;
    int half = ln >> 5;
    int gwave = blockIdx.x * 4 + wid;

    // ---- prep (per-lane: one (pixel,k)) ----
    int k = ln & 31;
    int pix = gwave * 2 + half;
    const float* fp = flow + (size_t)pix * 64 + 2 * k;
    float gy = __builtin_nontemporal_load(fp);
    float gx = __builtin_nontemporal_load(fp + 1);
    float ix = fmaf(gx, 1024.f, 1023.5f);
    float iy = fmaf(gy, 32.f, 31.5f);
    float xf = floorf(ix), yf = floorf(iy);
    float wx = ix - xf, wy = iy - yf;
    int x0 = (int)xf, y0 = (int)yf;
    bool xv0 = (unsigned)x0 < (unsigned)WR;
    bool xv1 = (unsigned)(x0 + 1) < (unsigned)WR;
    bool yv0 = (unsigned)y0 < (unsigned)HR;
    bool yv1 = (unsigned)(y0 + 1) < (unsigned)HR;
    int xc0 = x0 < 0 ? 0 : x0;
    int xc1 = x0 + 1 > WR - 1 ? WR - 1 : x0 + 1;
    int yc0 = y0 < 0 ? 0 : y0;
    int yc1 = y0 + 1 > HR - 1 ? HR - 1 : y0 + 1;
    uint o00 = (xv0 && yv0) ? (uint)(((yc0 << 11) + xc0) << 7) : ZOFF;
    uint o01 = (xv1 && yv0) ? (uint)(((yc0 << 11) + xc1) << 7) : ZOFF;
    uint o10 = (xv0 && yv1) ? (uint)(((yc1 << 11) + xc0) << 7) : ZOFF;
    uint o11 = (xv1 && yv1) ? (uint)(((yc1 << 11) + xc1) << 7) : ZOFF;
    float w00 = (1.f - wy) * (1.f - wx);
    float w01 = (1.f - wy) * wx;
    float w10 = wy * (1.f - wx);
    float w11 = wy * wx;

    // ---- 2-way partition by slice (in-range compacted to front) ----
    bool isIn = ((yc0 >> 5) == sel);
    unsigned long long hm = half ? 0xFFFFFFFF00000000ull : 0x00000000FFFFFFFFull;
    unsigned long long lower = (1ull << ln) - 1ull;
    unsigned long long balIn = __ballot(isIn);
    int cntIn = __popcll(balIn & hm);
    int rankIn = __popcll(balIn & hm & lower);
    int rankOut = __popcll(~balIn & hm & lower);
    int pos = isIn ? rankIn : (cntIn + rankOut);
    *(int4_*)&pbuf[wid][half][pos][0] =
        (int4_){(int)o00, __float_as_int(w00), (int)o01, __float_as_int(w01)};
    *(int4_*)&pbuf[wid][half][pos][4] =
        (int4_){(int)o10, __float_as_int(w10), (int)o11, __float_as_int(w11)};
    if ((ln & 31) == 0) {                                // dummy entry at pos 32
        *(int4_*)&pbuf[wid][half][32][0] =
            (int4_){(int)NEGOFF, __float_as_int(1.0f), (int)ZOFF, 0};
        *(int4_*)&pbuf[wid][half][32][4] = (int4_){(int)ZOFF, 0, (int)ZOFF, 0};
    }
    __syncthreads();

    uint laneByte = (uint)((ln & 31) * 4);
    const uint* pb = &pbuf[wid][half][0][0];
    float mLo = -3.0e38f, mHi = -3.0e38f;
    int cA = __builtin_amdgcn_readlane(cntIn, 0);
    int cB = __builtin_amdgcn_readlane(cntIn, 32);
    int trip = cA > cB ? cA : cB;

    for (int i = 0; i < trip; i++) {
        int idx = (i < cntIn) ? i : 32;
        const uint* e = pb + idx * 8;
        uint2 e0 = *(const uint2*)(e + 0);               // ds_read_b64, bcast/half
        uint2 e1 = *(const uint2*)(e + 2);
        uint2 e2 = *(const uint2*)(e + 4);
        uint2 e3 = *(const uint2*)(e + 6);
        uint d0 = *(const uint*)(rftb + (e0.x + laneByte));
        uint d1 = *(const uint*)(rftb + (e1.x + laneByte));
        uint d2 = *(const uint*)(rftb + (e2.x + laneByte));
        uint d3 = *(const uint*)(rftb + (e3.x + laneByte));
        float W0 = __uint_as_float(e0.y);
        float W1 = __uint_as_float(e1.y);
        float W2 = __uint_as_float(e2.y);
        float W3 = __uint_as_float(e3.y);

        float vlo = W0 * __uint_as_float(d0 << 16);
        vlo = fmaf(W1, __uint_as_float(d1 << 16), vlo);
        vlo = fmaf(W2, __uint_as_float(d2 << 16), vlo);
        vlo = fmaf(W3, __uint_as_float(d3 << 16), vlo);
        float vhi = W0 * __uint_as_float(d0 & 0xffff0000u);
        vhi = fmaf(W1, __uint_as_float(d1 & 0xffff0000u), vhi);
        vhi = fmaf(W2, __uint_as_float(d2 & 0xffff0000u), vhi);
        vhi = fmaf(W3, __uint_as_float(d3 & 0xffff0000u), vhi);
        mLo = fmaxf(mLo, vlo);
        mHi = fmaxf(mHi, vhi);
    }

    uint* xp = (uint*)((char*)xin + (size_t)pix * 256 + 128 + (ln & 31) * 4);
    if (mergePrev) {                                     // merge dispatch A's max
        uint cur = __builtin_nontemporal_load(xp);
        mLo = fmaxf(mLo, __uint_as_float(cur << 16));
        mHi = fmaxf(mHi, __uint_as_float(cur & 0xffff0000u));
    }
    uint outw;
    asm("v_cvt_pk_bf16_f32 %0, %1, %2" : "=v"(outw) : "v"(mLo), "v"(mHi));
    __builtin_nontemporal_store(outw, xp);
}

// ---------------------------------------------------------------------------
// conv1: implicit-GEMM MFMA, M=64(o), N=192 (180-px half-row + pad), K=1152.
// Input xin bf16 [p][128]. Output res_bf BF16 [p][64] (BN+ReLU applied).
// ---------------------------------------------------------------------------
__global__ __launch_bounds__(256) void k_mconv1(const ushort* __restrict__ xin,
                                                const ushort* __restrict__ wA,
                                                const float* __restrict__ g,
                                                const float* __restrict__ b,
                                                const float* __restrict__ mn,
                                                const float* __restrict__ vr,
                                                ushort* __restrict__ res_bf) {
    __shared__ __align__(16) ushort xt[3][194][32];
    int tid = threadIdx.x;
    int h = blockIdx.x >> 1, w0 = (blockIdx.x & 1) * 180;
    int wid = tid >> 6, ln = tid & 63;
    f32x4 acc[4][3];
    #pragma unroll
    for (int m = 0; m < 4; m++)
        #pragma unroll
        for (int nf = 0; nf < 3; nf++) acc[m][nf] = (f32x4){0.f, 0.f, 0.f, 0.f};

    for (int c = 0; c < 4; c++) {
        __syncthreads();
        for (int i = tid; i < 2184; i += 256) {          // 546 slots x 4 quads
            int q = i & 3, s = i >> 2;
            int r = s / 182, pw = s - r * 182;
            int gh = h + r - 1;
            int gw = w0 + pw - 1;
            if (gw < 0) gw += WW;
            if (gw >= WW) gw -= WW;
            int4_ val = {0, 0, 0, 0};
            if ((unsigned)gh < (unsigned)HH)
                val = *(const int4_*)(xin + ((size_t)(gh * WW + gw) * 128 + c * 32 + q * 8));
            *(int4_*)&xt[r][pw][(q ^ (pw & 3)) * 8] = val;
        }
        __syncthreads();
        #pragma unroll
        for (int tap = 0; tap < 9; tap++) {
            int dh = tap / 3, dw = tap % 3;
            short8 aF[4];
            #pragma unroll
            for (int m = 0; m < 4; m++)
                aF[m] = *(const short8*)(wA + (size_t)(((c * 9 + tap) * 4 + m) * 64 + ln) * 8);
            short8 bF[3];
            #pragma unroll
            for (int nf = 0; nf < 3; nf++) {
                int pw = wid * 48 + nf * 16 + (ln & 15) + dw;
                bF[nf] = *(const short8*)&xt[dh][pw][((((ln >> 4) & 3)) ^ (pw & 3)) * 8];
            }
            #pragma unroll
            for (int m = 0; m < 4; m++)
                #pragma unroll
                for (int nf = 0; nf < 3; nf++)
                    acc[m][nf] = __builtin_amdgcn_mfma_f32_16x16x32_bf16(aF[m], bF[nf], acc[m][nf], 0, 0, 0);
        }
    }
    // epilogue: BN + ReLU -> res_bf[p][o] (bf16, paired stores)
    #pragma unroll
    for (int m = 0; m < 4; m++) {
        int ob = m * 16 + ((ln >> 4) & 3) * 4;
        float sc0 = g[ob]     * rsqrtf(vr[ob]     + 1e-5f);
        float sc1 = g[ob + 1] * rsqrtf(vr[ob + 1] + 1e-5f);
        float sc2 = g[ob + 2] * rsqrtf(vr[ob + 2] + 1e-5f);
        float sc3 = g[ob + 3] * rsqrtf(vr[ob + 3] + 1e-5f);
        float bi0 = b[ob]     - mn[ob]     * sc0;
        float bi1 = b[ob + 1] - mn[ob + 1] * sc1;
        float bi2 = b[ob + 2] - mn[ob + 2] * sc2;
        float bi3 = b[ob + 3] - mn[ob + 3] * sc3;
        #pragma unroll
        for (int nf = 0; nf < 3; nf++) {
            int n = wid * 48 + nf * 16 + (ln & 15);
            if (n < 180) {
                int P = h * WW + w0 + n;
                float v0 = fmaxf(fmaf(acc[m][nf][0], sc0, bi0), 0.f);
                float v1 = fmaxf(fmaf(acc[m][nf][1], sc1, bi1), 0.f);
                float v2 = fmaxf(fmaf(acc[m][nf][2], sc2, bi2), 0.f);
                float v3 = fmaxf(fmaf(acc[m][nf][3], sc3, bi3), 0.f);
                uint lo, hi;
                asm("v_cvt_pk_bf16_f32 %0, %1, %2" : "=v"(lo) : "v"(v0), "v"(v1));
                asm("v_cvt_pk_bf16_f32 %0, %1, %2" : "=v"(hi) : "v"(v2), "v"(v3));
                uint2 pk; pk.x = lo; pk.y = hi;
                *(uint2*)(res_bf + (size_t)P * 64 + ob) = pk;
            }
        }
    }
}

// ---------------------------------------------------------------------------
// conv2: same GEMM (K=576) on res_bf (bf16, staged raw), BN + channel
// softmax + final out = polar + res*att.
// ---------------------------------------------------------------------------
__global__ __launch_bounds__(256) void k_mconv2(const ushort* __restrict__ res_bf,
                                                const float* __restrict__ polar,
                                                const ushort* __restrict__ wA,
                                                const float* __restrict__ g,
                                                const float* __restrict__ b,
                                                const float* __restrict__ mn,
                                                const float* __restrict__ vr,
                                                float* __restrict__ out) {
    __shared__ __align__(16) ushort xt[3][194][32];
    int tid = threadIdx.x;
    int h = blockIdx.x >> 1, w0 = (blockIdx.x & 1) * 180;
    int wid = tid >> 6, ln = tid & 63;
    f32x4 acc[4][3];
    #pragma unroll
    for (int m = 0; m < 4; m++)
        #pragma unroll
        for (int nf = 0; nf < 3; nf++) acc[m][nf] = (f32x4){0.f, 0.f, 0.f, 0.f};

    for (int c = 0; c < 2; c++) {
        __syncthreads();
        for (int i = tid; i < 2184; i += 256) {
            int q = i & 3, s = i >> 2;
            int r = s / 182, pw = s - r * 182;
            int gh = h + r - 1;
            int gw = w0 + pw - 1;
            if (gw < 0) gw += WW;
            if (gw >= WW) gw -= WW;
            int4_ val = {0, 0, 0, 0};
            if ((unsigned)gh < (unsigned)HH)
                val = *(const int4_*)(res_bf + ((size_t)(gh * WW + gw) * 64 + c * 32 + q * 8));
            *(int4_*)&xt[r][pw][(q ^ (pw & 3)) * 8] = val;
        }
        __syncthreads();
        #pragma unroll
        for (int tap = 0; tap < 9; tap++) {
            int dh = tap / 3, dw = tap % 3;
            short8 aF[4];
            #pragma unroll
            for (int m = 0; m < 4; m++)
                aF[m] = *(const short8*)(wA + (size_t)(((c * 9 + tap) * 4 + m) * 64 + ln) * 8);
            short8 bF[3];
            #pragma unroll
            for (int nf = 0; nf < 3; nf++) {
                int pw = wid * 48 + nf * 16 + (ln & 15) + dw;
                bF[nf] = *(const short8*)&xt[dh][pw][((((ln >> 4) & 3)) ^ (pw & 3)) * 8];
            }
            #pragma unroll
            for (int m = 0; m < 4; m++)
                #pragma unroll
                for (int nf = 0; nf < 3; nf++)
                    acc[m][nf] = __builtin_amdgcn_mfma_f32_16x16x32_bf16(aF[m], bF[nf], acc[m][nf], 0, 0, 0);
        }
    }
    // epilogue: BN -> softmax over 64 channels -> out = polar + res*att
    #pragma unroll
    for (int m = 0; m < 4; m++) {
        #pragma unroll
        for (int reg = 0; reg < 4; reg++) {
            int o = m * 16 + ((ln >> 4) & 3) * 4 + reg;
            float sc = g[o] * rsqrtf(vr[o] + 1e-5f);
            float bi = b[o] - mn[o] * sc;
            #pragma unroll
            for (int nf = 0; nf < 3; nf++)
                acc[m][nf][reg] = fmaf(acc[m][nf][reg], sc, bi);
        }
    }
    #pragma unroll
    for (int nf = 0; nf < 3; nf++) {
        float mx = -3.0e38f;
        #pragma unroll
        for (int m = 0; m < 4; m++)
            #pragma unroll
            for (int reg = 0; reg < 4; reg++) mx = fmaxf(mx, acc[m][nf][reg]);
        mx = fmaxf(mx, __shfl_xor(mx, 16));
        mx = fmaxf(mx, __shfl_xor(mx, 32));
        float s = 0.f;
        #pragma unroll
        for (int m = 0; m < 4; m++)
            #pragma unroll
            for (int reg = 0; reg < 4; reg++) {
                float e = __expf(acc[m][nf][reg] - mx);
                acc[m][nf][reg] = e;
                s += e;
            }
        s += __shfl_xor(s, 16);
        s += __shfl_xor(s, 32);
        float rinv = 1.f / s;
        int n = wid * 48 + nf * 16 + (ln & 15);
        if (n < 180) {
            int P = h * WW + w0 + n;
            #pragma unroll
            for (int m = 0; m < 4; m++)
                #pragma unroll
                for (int reg = 0; reg < 4; reg++) {
                    int o = m * 16 + ((ln >> 4) & 3) * 4 + reg;
                    float att = acc[m][nf][reg] * rinv;
                    float rv = __uint_as_float((uint)res_bf[(size_t)P * 64 + o] << 16);
                    out[(size_t)o * NPIX + P] =
                        fmaf(rv, att, polar[(size_t)o * NPIX + P]);
                }
        }
    }
}

// ---------------------------------------------------------------------------
extern "C" void kernel_launch(void* const* d_in, const int* in_sizes, int n_in,
                              void* d_out, int out_size, void* d_ws, size_t ws_size,
                              hipStream_t stream) {
    const float* flow  = (const float*)d_in[0];
    const float* polar = (const float*)d_in[1];
    const float* rf    = (const float*)d_in[2];
    const float* fw    = (const float*)d_in[3];
    const float* fg    = (const float*)d_in[4];
    const float* fb    = (const float*)d_in[5];
    const float* fm    = (const float*)d_in[6];
    const float* fv    = (const float*)d_in[7];
    const float* aw    = (const float*)d_in[8];
    const float* ag    = (const float*)d_in[9];
    const float* ab    = (const float*)d_in[10];
    const float* am    = (const float*)d_in[11];
    const float* av    = (const float*)d_in[12];
    float* out = (float*)d_out;

    char* wsb = (char*)d_ws;
    ushort* xin    = (ushort*)wsb;                        // [NPIX][128] bf16 = 44,236,800 B
    ushort* rft    = (ushort*)(wsb + 44236800);           // [RFNPIX][64] bf16 + sentinel lines
    ushort* res_bf = (ushort*)(wsb + 61014272);           // [NPIX][64] bf16 = 22,118,400 B
    ushort* wA1    = (ushort*)(wsb + 83132672);           // 147,456 B
    ushort* wA2    = wA1 + 73728;                         // 73,728 B

    k_wprep<<<432, 256, 0, stream>>>(fw, aw, wA1, wA2);
    k_tr<<<NPIX / 64, 256, 0, stream>>>(polar, xin, NPIX, 128);
    k_tr<<<RFNPIX / 64, 256, 0, stream>>>(rf, rft, RFNPIX, 64);
    k_zero<<<1, 64, 0, stream>>>((uint*)rft);
    k_sample<<<NPIX / 8, 256, 0, stream>>>(flow, (const char*)rft, xin, 0, 0);
    k_sample<<<NPIX / 8, 256, 0, stream>>>(flow, (const char*)rft, xin, 1, 1);
    k_mconv1<<<960, 256, 0, stream>>>(xin, wA1, fg, fb, fm, fv, res_bf);
    k_mconv2<<<960, 256, 0, stream>>>(res_bf, polar, wA2, ag, ab, am, av, out);
}